// Round 2
// baseline (1095.324 us; speedup 1.0000x reference)
//
#include <hip/hip_runtime.h>

#define SEQ   2048
#define BATCH 256
#define INDIM 64
#define HID   128

struct F2 { float x, y; };

// Permuted value via DPP. CTRL: 0xB1 quad_perm xor1, 0x4E quad_perm xor2,
// 0x124 row_ror:4, 0x128 row_ror:8.
template <int CTRL>
__device__ __forceinline__ float dpp_get(float v) {
    int t = __builtin_amdgcn_update_dpp(0, __builtin_bit_cast(int, v),
                                        CTRL, 0xF, 0xF, true);
    return __builtin_bit_cast(float, t);
}

// Packed fp32 math (VOP3P): 2 FMAs/lane/inst.
#define PK_MUL(d, a, b) asm("v_pk_mul_f32 %0, %1, %2"     : "=v"(d) : "v"(a), "v"(b))
#define PK_FMA(d, a, b) asm("v_pk_fma_f32 %0, %1, %2, %0" : "+v"(d) : "v"(a), "v"(b))

// tanh(d + bias) with bias pre-folded: m = d*K + bias*K, K = -2/ln2;
// e = 2^m = e^{-2(d+bias)}; tanh = (1-e)/(1+e).
#define TANH_K (-2.885390081777927f)
__device__ __forceinline__ float tanh_pre(float d, float bias_k) {
    float m = __builtin_fmaf(d, TANH_K, bias_k);
    float e = __builtin_amdgcn_exp2f(m);
    return (1.0f - e) * __builtin_amdgcn_rcpf(1.0f + e);
}

// R12: TWO batch chains PER LANE (ILP, not TLP). Shell identical to the
// proven 605us kernel: 512 thr, 8 waves, 2/SIMD, 16-way k-split, one
// barrier/step. Weights+bias are shared by both chains (zero extra VGPRs);
// the two chains' serial paths (ds_read -> 12-deep FMA chain -> 5-DPP
// butterfly -> tanh) interleave inside one instruction stream, hiding
// latency without touching occupancy or barrier structure (R11 lesson:
// wave-level co-location is defeated by the shared s_barrier + AGPR parking).
__global__ __launch_bounds__(512)
__attribute__((amdgpu_waves_per_eu(2, 2)))   // proven allocation regime
void rnn_fused(
    const float* __restrict__ x,    // (S,B,IN)
    const float* __restrict__ Wx,   // (H,IN)
    const float* __restrict__ bx,   // (H)
    const float* __restrict__ Wh,   // (H,H)
    const float* __restrict__ bh,   // (H)
    float* __restrict__ out)        // (S,B,H) then (1,B,H)
{
    const int b0  = blockIdx.x * 2;  // chains b0, b0+1
    const int tid = threadIdx.x;     // 0..511 (8 waves, 2/SIMD)
    const int l   = tid & 63;
    const int w   = tid >> 6;
    const int s   = l & 15;          // k-slice: h[4s..4s+3], h[64+4s..+3], x[4s..+3]
    const int j0  = w * 16 + (l >> 4) * 4;   // group base: outputs j0..j0+3

    __shared__ __align__(16) float hbuf[2][2][HID];   // [chain][bank][h]

    // ---- weights as packed float-pairs, SLOT-PERMUTED: accumulator slot o
    // holds output j0 + (o ^ (l&3)) -> cndmask-free butterfly.
    const double* WhD = (const double*)Wh;   // 64 doubles per row
    const double* WxD = (const double*)Wx;   // 32 doubles per row
    double wA[4], wB[4], wC[4], wD[4], wX[4], wY[4];
#pragma unroll
    for (int o = 0; o < 4; ++o) {
        const int row = j0 + (o ^ (l & 3));        // slot-permuted output row
        const int r   = row * 64 + 2 * s;
        wA[o] = WhD[r];      wB[o] = WhD[r + 1];
        wC[o] = WhD[r + 32]; wD[o] = WhD[r + 33];
        const int rx  = row * 32 + 2 * s;
        wX[o] = WxD[rx];     wY[o] = WxD[rx + 1];
    }
    const int jj = j0 + (l & 3);          // output this lane holds after reduce
    float bias_k = (bx[jj] + bh[jj]) * TANH_K;   // shared by both chains

    ((float*)hbuf)[tid] = 0.0f;          // 512 threads zero all 512 floats
    __syncthreads();

    // x in registers: per-thread double2 (=float4) slice per chain, 4-step
    // banks, double-buffered. Chains are adjacent in B -> +INDIM floats.
    const double2* xb2a = (const double2*)(x + (size_t)b0 * INDIM + 4 * s);
    const double2* xb2b = (const double2*)(x + (size_t)(b0 + 1) * INDIM + 4 * s);
    const size_t   S2   = (size_t)BATCH * INDIM / 4;   // double2 per timestep
    double2 xaA[4], xnA[4], xaB[4], xnB[4];
#pragma unroll
    for (int i = 0; i < 4; ++i) {
        xaA[i] = xb2a[(size_t)i * S2];
        xaB[i] = xb2b[(size_t)i * S2];
    }

    float* outp = out + (size_t)b0 * HID + jj;  // chain1 store = outp + HID
    const bool wr = (s < 4);                    // 16 lanes/wave write
    float hvA = 0.0f, hvB = 0.0f;

    for (int tb = 0; tb < SEQ; tb += 4) {
        // In-loop pin (once per 4 steps): loop-carried "+v" keeps weights
        // VGPR-resident — no AGPR parking, no remat.
        asm volatile("" : "+v"(wA[0]), "+v"(wA[1]), "+v"(wA[2]), "+v"(wA[3]));
        asm volatile("" : "+v"(wB[0]), "+v"(wB[1]), "+v"(wB[2]), "+v"(wB[3]));
        asm volatile("" : "+v"(wC[0]), "+v"(wC[1]), "+v"(wC[2]), "+v"(wC[3]));
        asm volatile("" : "+v"(wD[0]), "+v"(wD[1]), "+v"(wD[2]), "+v"(wD[3]));
        asm volatile("" : "+v"(wX[0]), "+v"(wX[1]), "+v"(wX[2]), "+v"(wX[3]));
        asm volatile("" : "+v"(wY[0]), "+v"(wY[1]), "+v"(wY[2]), "+v"(wY[3]));
        asm volatile("" : "+v"(bias_k));

        // issue next bank for both chains (steps tb+4..tb+7, tail-clamped)
#pragma unroll
        for (int i = 0; i < 4; ++i) {
            int tp = tb + 4 + i; if (tp > SEQ - 1) tp = SEQ - 1;
            xnA[i] = xb2a[(size_t)tp * S2];
            xnB[i] = xb2b[(size_t)tp * S2];
        }

#pragma unroll
        for (int q = 0; q < 4; ++q) {
            const double2* hbdA = (const double2*)&hbuf[0][q & 1][0];
            const double2* hbdB = (const double2*)&hbuf[1][q & 1][0];

            // 4 ds_read_b128, 4-way g-broadcast — conflict-free
            const double2 H0A = hbdA[s];
            const double2 H1A = hbdA[16 + s];
            const double2 H0B = hbdB[s];
            const double2 H1B = hbdB[16 + s];
            const double2 XA  = xaA[q];
            const double2 XB  = xaB[q];

            double pa0, pa1, pa2, pa3;   // chain A accumulators
            double pb0, pb1, pb2, pb3;   // chain B accumulators
            // x first (independent of h -> schedules into ds_read shadow);
            // A/B interleaved pairwise: two independent dep-chains in flight.
            PK_MUL(pa0, XA.x, wX[0]); PK_MUL(pb0, XB.x, wX[0]);
            PK_MUL(pa1, XA.x, wX[1]); PK_MUL(pb1, XB.x, wX[1]);
            PK_MUL(pa2, XA.x, wX[2]); PK_MUL(pb2, XB.x, wX[2]);
            PK_MUL(pa3, XA.x, wX[3]); PK_MUL(pb3, XB.x, wX[3]);
            PK_FMA(pa0, XA.y, wY[0]); PK_FMA(pb0, XB.y, wY[0]);
            PK_FMA(pa1, XA.y, wY[1]); PK_FMA(pb1, XB.y, wY[1]);
            PK_FMA(pa2, XA.y, wY[2]); PK_FMA(pb2, XB.y, wY[2]);
            PK_FMA(pa3, XA.y, wY[3]); PK_FMA(pb3, XB.y, wY[3]);
            PK_FMA(pa0, H0A.x, wA[0]); PK_FMA(pb0, H0B.x, wA[0]);
            PK_FMA(pa1, H0A.x, wA[1]); PK_FMA(pb1, H0B.x, wA[1]);
            PK_FMA(pa2, H0A.x, wA[2]); PK_FMA(pb2, H0B.x, wA[2]);
            PK_FMA(pa3, H0A.x, wA[3]); PK_FMA(pb3, H0B.x, wA[3]);
            PK_FMA(pa0, H0A.y, wB[0]); PK_FMA(pb0, H0B.y, wB[0]);
            PK_FMA(pa1, H0A.y, wB[1]); PK_FMA(pb1, H0B.y, wB[1]);
            PK_FMA(pa2, H0A.y, wB[2]); PK_FMA(pb2, H0B.y, wB[2]);
            PK_FMA(pa3, H0A.y, wB[3]); PK_FMA(pb3, H0B.y, wB[3]);
            PK_FMA(pa0, H1A.x, wC[0]); PK_FMA(pb0, H1B.x, wC[0]);
            PK_FMA(pa1, H1A.x, wC[1]); PK_FMA(pb1, H1B.x, wC[1]);
            PK_FMA(pa2, H1A.x, wC[2]); PK_FMA(pb2, H1B.x, wC[2]);
            PK_FMA(pa3, H1A.x, wC[3]); PK_FMA(pb3, H1B.x, wC[3]);
            PK_FMA(pa0, H1A.y, wD[0]); PK_FMA(pb0, H1B.y, wD[0]);
            PK_FMA(pa1, H1A.y, wD[1]); PK_FMA(pb1, H1B.y, wD[1]);
            PK_FMA(pa2, H1A.y, wD[2]); PK_FMA(pb2, H1B.y, wD[2]);
            PK_FMA(pa3, H1A.y, wD[3]); PK_FMA(pb3, H1B.y, wD[3]);

            float aA0, aA1, aA2, aA3, aB0, aB1, aB2, aB3;
            { F2 u = __builtin_bit_cast(F2, pa0); aA0 = u.x + u.y; }
            { F2 u = __builtin_bit_cast(F2, pa1); aA1 = u.x + u.y; }
            { F2 u = __builtin_bit_cast(F2, pa2); aA2 = u.x + u.y; }
            { F2 u = __builtin_bit_cast(F2, pa3); aA3 = u.x + u.y; }
            { F2 u = __builtin_bit_cast(F2, pb0); aB0 = u.x + u.y; }
            { F2 u = __builtin_bit_cast(F2, pb1); aB1 = u.x + u.y; }
            { F2 u = __builtin_bit_cast(F2, pb2); aB2 = u.x + u.y; }
            { F2 u = __builtin_bit_cast(F2, pb3); aB3 = u.x + u.y; }

            // cndmask-free butterfly ×2 (independent dep-chains interleave)
            float cA0 = aA0 + dpp_get<0xB1>(aA1);
            float cB0 = aB0 + dpp_get<0xB1>(aB1);
            float cA1 = aA2 + dpp_get<0xB1>(aA3);
            float cB1 = aB2 + dpp_get<0xB1>(aB3);
            float dA  = cA0 + dpp_get<0x4E>(cA1);
            float dB  = cB0 + dpp_get<0x4E>(cB1);
            dA += dpp_get<0x124>(dA);
            dB += dpp_get<0x124>(dB);
            dA += dpp_get<0x128>(dA);
            dB += dpp_get<0x128>(dB);

            hvA = tanh_pre(dA, bias_k);
            hvB = tanh_pre(dB, bias_k);

            if (wr) {                      // 16 lanes/wave, contiguous dwords
                hbuf[0][(q + 1) & 1][jj] = hvA;
                hbuf[1][(q + 1) & 1][jj] = hvB;
                *outp        = hvA;        // stores never block
                *(outp + HID) = hvB;
            }
            outp += BATCH * HID;

            // h-exchange sync only: lgkmcnt(0) -> ds_writes visible; raw
            // s_barrier is opaque to SIInsertWaitcnts (no hidden vmcnt(0)).
            asm volatile("s_waitcnt lgkmcnt(0)" ::: "memory");
            asm volatile("s_barrier" ::: "memory");
        }

        // rotate banks (vmcnt wait lands here, ~4 steps after issue)
#pragma unroll
        for (int i = 0; i < 4; ++i) { xaA[i] = xnA[i]; xaB[i] = xnB[i]; }
    }

    // final state (1,B,H): peeled from the loop
    if (wr) {
        out[(size_t)SEQ * BATCH * HID + (size_t)b0 * HID + jj]       = hvA;
        out[(size_t)SEQ * BATCH * HID + (size_t)(b0 + 1) * HID + jj] = hvB;
    }
}

extern "C" void kernel_launch(void* const* d_in, const int* in_sizes, int n_in,
                              void* d_out, int out_size, void* d_ws, size_t ws_size,
                              hipStream_t stream) {
    const float* x  = (const float*)d_in[0];
    const float* Wx = (const float*)d_in[1];
    const float* bx = (const float*)d_in[2];
    const float* Wh = (const float*)d_in[3];
    const float* bh = (const float*)d_in[4];
    float* out = (float*)d_out;
    (void)in_sizes; (void)n_in; (void)d_ws; (void)ws_size; (void)out_size;
    rnn_fused<<<dim3(BATCH / 2), dim3(512), 0, stream>>>(x, Wx, bx, Wh, bh, out);
}

// Round 3
// 633.128 us; speedup vs baseline: 1.7300x; 1.7300x over previous
//
#include <hip/hip_runtime.h>

#define SEQ   2048
#define BATCH 256
#define INDIM 64
#define HID   128

struct F2 { float x, y; };

// Permuted value via DPP. CTRL: 0xB1 quad_perm xor1, 0x4E quad_perm xor2,
// 0x124 row_ror:4, 0x128 row_ror:8.
template <int CTRL>
__device__ __forceinline__ float dpp_get(float v) {
    int t = __builtin_amdgcn_update_dpp(0, __builtin_bit_cast(int, v),
                                        CTRL, 0xF, 0xF, true);
    return __builtin_bit_cast(float, t);
}

// Packed fp32 math (VOP3P): 2 FMAs/lane/inst.
#define PK_MUL(d, a, b) asm("v_pk_mul_f32 %0, %1, %2"     : "=v"(d) : "v"(a), "v"(b))
#define PK_FMA(d, a, b) asm("v_pk_fma_f32 %0, %1, %2, %0" : "+v"(d) : "v"(a), "v"(b))

// tanh(d + bias) with bias pre-folded: m = d*K + bias*K, K = -2/ln2;
// e = 2^m = e^{-2(d+bias)}; tanh = (1-e)/(1+e).
#define TANH_K (-2.885390081777927f)
__device__ __forceinline__ float tanh_pre(float d, float bias_k) {
    float m = __builtin_fmaf(d, TANH_K, bias_k);
    float e = __builtin_amdgcn_exp2f(m);
    return (1.0f - e) * __builtin_amdgcn_rcpf(1.0f + e);
}

// R13: 4 waves x 32 outputs (was 8 x 16). Single chain per block (R11/R12
// lesson: extra chains fail via barrier lockstep resp. AGPR parking).
// Per-step LDS read service halves (8 ds_read_b128 wave-insts, was 16),
// barrier domain halves (4 waves), per-SIMD VALU issue unchanged
// (1 wave x 8 slots == 2 waves x 4 slots). Per-lane shape is the proven
// 604us kernel with TWO independent 4-slot slot-permuted butterflies.
__global__ __launch_bounds__(256)
__attribute__((amdgpu_waves_per_eu(1, 1)))   // cap 512 VGPR: no AGPR parking
void rnn_fused(
    const float* __restrict__ x,    // (S,B,IN)
    const float* __restrict__ Wx,   // (H,IN)
    const float* __restrict__ bx,   // (H)
    const float* __restrict__ Wh,   // (H,H)
    const float* __restrict__ bh,   // (H)
    float* __restrict__ out)        // (S,B,H) then (1,B,H)
{
    const int b   = blockIdx.x;
    const int tid = threadIdx.x;     // 0..255 (4 waves, 1/SIMD)
    const int l   = tid & 63;
    const int w   = tid >> 6;        // 0..3
    const int s   = l & 15;          // k-slice: h[4s..4s+3], h[64+4s..+3], x[4s..+3]
    const int j0  = w * 32 + (l >> 4) * 8;   // group base: outputs j0..j0+7

    __shared__ __align__(16) float hbuf[2][HID];   // double-buffered h

    // ---- weights as packed float-pairs, SLOT-PERMUTED: slot o (two banks
    // of 4) holds output j0 + (o&4) + ((o&3) ^ (l&3)) -> two cndmask-free
    // butterflies per lane.
    const double* WhD = (const double*)Wh;   // 64 doubles per row
    const double* WxD = (const double*)Wx;   // 32 doubles per row
    double wA[8], wB[8], wC[8], wD[8], wX[8], wY[8];
#pragma unroll
    for (int o = 0; o < 8; ++o) {
        const int row = j0 + (o & 4) + ((o & 3) ^ (l & 3));
        const int r   = row * 64 + 2 * s;
        wA[o] = WhD[r];      wB[o] = WhD[r + 1];
        wC[o] = WhD[r + 32]; wD[o] = WhD[r + 33];
        const int rx  = row * 32 + 2 * s;
        wX[o] = WxD[rx];     wY[o] = WxD[rx + 1];
    }
    const int jj  = j0 + (l & 3);        // bank-0 output; bank-1 is jj+4
    float bias_k  = (bx[jj]     + bh[jj])     * TANH_K;
    float bias_k2 = (bx[jj + 4] + bh[jj + 4]) * TANH_K;

    ((float*)hbuf)[tid] = 0.0f;          // 256 threads zero all 256 floats
    __syncthreads();

    // x in registers: per-thread double2 (=float4) slice, 4-step banks,
    // double-buffered. Compiler-placed vmcnt waits land at bank rotation.
    const double2* xb2 = (const double2*)(x + (size_t)b * INDIM + 4 * s);
    const size_t   S2  = (size_t)BATCH * INDIM / 4;   // double2 per timestep
    double2 xa[4], xn[4];
#pragma unroll
    for (int i = 0; i < 4; ++i) xa[i] = xb2[(size_t)i * S2];

    float* outp = out + (size_t)b * HID + jj;  // bank-1 store = outp[4]
    const bool wr = (s < 4);                   // 16 lanes/wave write
    float hv1 = 0.0f, hv2 = 0.0f;

    for (int tb = 0; tb < SEQ; tb += 4) {
        // In-loop pin (once per 4 steps): loop-carried "+v" keeps weights
        // VGPR-resident — no AGPR parking, no remat.
        asm volatile("" : "+v"(wA[0]), "+v"(wA[1]), "+v"(wA[2]), "+v"(wA[3]),
                          "+v"(wA[4]), "+v"(wA[5]), "+v"(wA[6]), "+v"(wA[7]));
        asm volatile("" : "+v"(wB[0]), "+v"(wB[1]), "+v"(wB[2]), "+v"(wB[3]),
                          "+v"(wB[4]), "+v"(wB[5]), "+v"(wB[6]), "+v"(wB[7]));
        asm volatile("" : "+v"(wC[0]), "+v"(wC[1]), "+v"(wC[2]), "+v"(wC[3]),
                          "+v"(wC[4]), "+v"(wC[5]), "+v"(wC[6]), "+v"(wC[7]));
        asm volatile("" : "+v"(wD[0]), "+v"(wD[1]), "+v"(wD[2]), "+v"(wD[3]),
                          "+v"(wD[4]), "+v"(wD[5]), "+v"(wD[6]), "+v"(wD[7]));
        asm volatile("" : "+v"(wX[0]), "+v"(wX[1]), "+v"(wX[2]), "+v"(wX[3]),
                          "+v"(wX[4]), "+v"(wX[5]), "+v"(wX[6]), "+v"(wX[7]));
        asm volatile("" : "+v"(wY[0]), "+v"(wY[1]), "+v"(wY[2]), "+v"(wY[3]),
                          "+v"(wY[4]), "+v"(wY[5]), "+v"(wY[6]), "+v"(wY[7]));
        asm volatile("" : "+v"(bias_k), "+v"(bias_k2));

        // issue next bank (steps tb+4..tb+7, clamped at the tail)
#pragma unroll
        for (int i = 0; i < 4; ++i) {
            int tp = tb + 4 + i; if (tp > SEQ - 1) tp = SEQ - 1;
            xn[i] = xb2[(size_t)tp * S2];
        }

#pragma unroll
        for (int q = 0; q < 4; ++q) {
            const double2* hbd = (const double2*)&hbuf[q & 1][0];

            // 2 ds_read_b128: granules s and 16+s, 4-way g-broadcast — conflict-free
            const double2 H0 = hbd[s];
            const double2 H1 = hbd[16 + s];
            const double2 X  = xa[q];

            double acc[8];
            // x first: independent of h -> schedules into ds_read shadow
#pragma unroll
            for (int o = 0; o < 8; ++o) PK_MUL(acc[o], X.x, wX[o]);
#pragma unroll
            for (int o = 0; o < 8; ++o) PK_FMA(acc[o], X.y, wY[o]);
#pragma unroll
            for (int o = 0; o < 8; ++o) PK_FMA(acc[o], H0.x, wA[o]);
#pragma unroll
            for (int o = 0; o < 8; ++o) PK_FMA(acc[o], H0.y, wB[o]);
#pragma unroll
            for (int o = 0; o < 8; ++o) PK_FMA(acc[o], H1.x, wC[o]);
#pragma unroll
            for (int o = 0; o < 8; ++o) PK_FMA(acc[o], H1.y, wD[o]);

            float a0, a1, a2, a3, a4, a5, a6, a7;
            { F2 u = __builtin_bit_cast(F2, acc[0]); a0 = u.x + u.y; }
            { F2 u = __builtin_bit_cast(F2, acc[1]); a1 = u.x + u.y; }
            { F2 u = __builtin_bit_cast(F2, acc[2]); a2 = u.x + u.y; }
            { F2 u = __builtin_bit_cast(F2, acc[3]); a3 = u.x + u.y; }
            { F2 u = __builtin_bit_cast(F2, acc[4]); a4 = u.x + u.y; }
            { F2 u = __builtin_bit_cast(F2, acc[5]); a5 = u.x + u.y; }
            { F2 u = __builtin_bit_cast(F2, acc[6]); a6 = u.x + u.y; }
            { F2 u = __builtin_bit_cast(F2, acc[7]); a7 = u.x + u.y; }

            // two cndmask-free butterflies (independent dep-chains interleave)
            float c0 = a0 + dpp_get<0xB1>(a1);
            float c2 = a4 + dpp_get<0xB1>(a5);
            float c1 = a2 + dpp_get<0xB1>(a3);
            float c3 = a6 + dpp_get<0xB1>(a7);
            float d1 = c0 + dpp_get<0x4E>(c1);
            float d2 = c2 + dpp_get<0x4E>(c3);
            d1 += dpp_get<0x124>(d1);
            d2 += dpp_get<0x124>(d2);
            d1 += dpp_get<0x128>(d1);
            d2 += dpp_get<0x128>(d2);

            hv1 = tanh_pre(d1, bias_k);
            hv2 = tanh_pre(d2, bias_k2);

            if (wr) {                      // 16 lanes/wave, 8 contiguous dwords/group
                hbuf[(q + 1) & 1][jj]     = hv1;   // merges to ds_write2_b32
                hbuf[(q + 1) & 1][jj + 4] = hv2;
                outp[0] = hv1;             // stores never block (no vmcnt waits)
                outp[4] = hv2;
            }
            outp += BATCH * HID;

            // h-exchange sync only: lgkmcnt(0) -> ds_writes visible; raw
            // s_barrier is opaque to SIInsertWaitcnts (no hidden vmcnt(0)).
            asm volatile("s_waitcnt lgkmcnt(0)" ::: "memory");
            asm volatile("s_barrier" ::: "memory");
        }

        // rotate banks (vmcnt wait lands here, ~4 steps after issue)
#pragma unroll
        for (int i = 0; i < 4; ++i) xa[i] = xn[i];
    }

    // final state (1,B,H): peeled from the loop
    if (wr) {
        out[(size_t)SEQ * BATCH * HID + (size_t)b * HID + jj]     = hv1;
        out[(size_t)SEQ * BATCH * HID + (size_t)b * HID + jj + 4] = hv2;
    }
}

extern "C" void kernel_launch(void* const* d_in, const int* in_sizes, int n_in,
                              void* d_out, int out_size, void* d_ws, size_t ws_size,
                              hipStream_t stream) {
    const float* x  = (const float*)d_in[0];
    const float* Wx = (const float*)d_in[1];
    const float* bx = (const float*)d_in[2];
    const float* Wh = (const float*)d_in[3];
    const float* bh = (const float*)d_in[4];
    float* out = (float*)d_out;
    (void)in_sizes; (void)n_in; (void)d_ws; (void)ws_size; (void)out_size;
    rnn_fused<<<dim3(BATCH), dim3(256), 0, stream>>>(x, Wx, bx, Wh, bh, out);
}